// Round 12
// baseline (174.894 us; speedup 1.0000x reference)
//
#include <hip/hip_runtime.h>

// Linear (kernelized) attention, N=8 L=S=8192 H=8 D=32, fp32.
// out = (Q'·(K'^T V)) / (Q'·Ksum + eps), Q'/K' = elu(x)+1.
// The /v_length and *v_length in the reference cancel exactly (2^13).

constexpr int N_ = 8, L_ = 8192, S_ = 8192, H_ = 8, D_ = 32;
constexpr int NH = N_ * H_;                  // 64 (n,h) pairs
constexpr int PART_STRIDE = D_ * D_ + D_;    // 1024 KV + 32 Ksum = 1056
constexpr int LCH = 256;                     // L-chunk per phase-2 block
constexpr float EPS_ = 1e-6f;
constexpr int HD = H_ * D_;                  // 256 floats = 1KB per (n,s) row

__device__ __forceinline__ float fmap(float x) {
    // elu(x)+1  (alpha=1): x>0 ? x+1 : exp(x)
    return x > 0.0f ? x + 1.0f : __expf(x);
}

// ---------------- phase 1: partial KV (D x D) + Ksum per (n,s-chunk) -------
// Copy-kernel-identical streams: one wave-beat = 64 lanes x float4 = ONE full
// (n,s) row (8 heads x 8 quads). Lane l holds K-quad and V-quad of head
// g=l>>3, quad q=l&7. Pure linear loads, no dup, no barriers in the loop.
// Cross-quad pairing via wave-private LDS: lane parks V-quad at XOR-swizzled
// slot (l&~7)|(q^g); reads back 8 broadcasts (conflict-free: bank 4*(q'^g)
// distinct per group). acc[4][32]/lane = this lane's 4 d-rows x all 32 v of
// its head. Ring depth 2 (4 x 1KB loads in flight/wave).
template<int SPL>
__global__ __launch_bounds__(256, 2) void lin_attn_phase1(
        const float* __restrict__ Kg, const float* __restrict__ Vg,
        float* __restrict__ part) {
    constexpr int CS_BLK = S_ / SPL;         // rows per block (64 @ SPL=128)
    constexpr int BEATS = CS_BLK / 4;        // beats per wave (16 @ SPL=128)
    const int n  = blockIdx.x / SPL;
    const int sc = blockIdx.x % SPL;
    const int t = threadIdx.x;
    const int w = t >> 6;             // wave 0..3
    const int l = t & 63;
    const int g = l >> 3;             // head of this lane's quads
    const int q = l & 7;              // quad index within the head-row

    __shared__ __align__(16) float4 vbuf[4][2][64];      // 8KB wave-private
    __shared__ __align__(16) float red4[4][64][36];      // 36KB, pad 36 vs 32

    float acc[4][32];                 // KV_g[4q+a][c], c=0..31
    #pragma unroll
    for (int a = 0; a < 4; ++a)
        #pragma unroll
        for (int c = 0; c < 32; ++c) acc[a][c] = 0.0f;
    float kp[4] = {0.f, 0.f, 0.f, 0.f};

    // wave w streams rows sc*CS_BLK + w + 4*i; lane reads quad l of the row
    const size_t base = (size_t)n * S_ * HD
                      + (size_t)(sc * CS_BLK + w) * HD + (l << 2);
    const float* kr = Kg + base;
    const float* vr = Vg + base;
    const int wr_slot = (l & ~7) | (q ^ g);

#define PROC(kq_, vq_, par) do {                                               \
        float kd[4];                                                           \
        kd[0] = fmap((kq_).x); kd[1] = fmap((kq_).y);                          \
        kd[2] = fmap((kq_).z); kd[3] = fmap((kq_).w);                          \
        kp[0] += kd[0]; kp[1] += kd[1]; kp[2] += kd[2]; kp[3] += kd[3];        \
        vbuf[w][par][wr_slot] = (vq_);                                         \
        _Pragma("unroll")                                                      \
        for (int qp = 0; qp < 8; ++qp) {                                       \
            const float4 vv = vbuf[w][par][(l & ~7) | (qp ^ g)];               \
            _Pragma("unroll")                                                  \
            for (int a = 0; a < 4; ++a) {                                      \
                acc[a][qp * 4 + 0] += kd[a] * vv.x;                            \
                acc[a][qp * 4 + 1] += kd[a] * vv.y;                            \
                acc[a][qp * 4 + 2] += kd[a] * vv.z;                            \
                acc[a][qp * 4 + 3] += kd[a] * vv.w;                            \
            }                                                                  \
        }                                                                      \
    } while (0)

    // 2-deep ring: beats i+1, i+2 in flight while beat i computes
    float4 kA = *reinterpret_cast<const float4*>(kr);
    float4 vA = *reinterpret_cast<const float4*>(vr);
    kr += 4 * HD; vr += 4 * HD;
    float4 kB = *reinterpret_cast<const float4*>(kr);
    float4 vB = *reinterpret_cast<const float4*>(vr);
    kr += 4 * HD; vr += 4 * HD;

    #pragma unroll 1
    for (int i = 0; i < (BEATS - 2) / 2; ++i) {
        PROC(kA, vA, 0);
        kA = *reinterpret_cast<const float4*>(kr);
        vA = *reinterpret_cast<const float4*>(vr);
        kr += 4 * HD; vr += 4 * HD;
        PROC(kB, vB, 1);
        kB = *reinterpret_cast<const float4*>(kr);
        vB = *reinterpret_cast<const float4*>(vr);
        kr += 4 * HD; vr += 4 * HD;
    }
    PROC(kA, vA, 0);
    PROC(kB, vB, 1);
#undef PROC

    // ---- cross-wave reduce (once), 4 rounds over acc-row a ----
    const int l2 = t & 63, cb = (t >> 6) * 8;
    #pragma unroll 1
    for (int a = 0; a < 4; ++a) {
        __syncthreads();   // previous round's reads (or main loop) done
        #pragma unroll
        for (int c4 = 0; c4 < 8; ++c4)
            *reinterpret_cast<float4*>(&red4[w][l][c4 * 4]) =
                make_float4(acc[a][c4 * 4], acc[a][c4 * 4 + 1],
                            acc[a][c4 * 4 + 2], acc[a][c4 * 4 + 3]);
        __syncthreads();
        float4 s0 = make_float4(0.f, 0.f, 0.f, 0.f);
        float4 s1 = make_float4(0.f, 0.f, 0.f, 0.f);
        #pragma unroll
        for (int w2 = 0; w2 < 4; ++w2) {
            const float4 r0 = *reinterpret_cast<const float4*>(&red4[w2][l2][cb]);
            const float4 r1 = *reinterpret_cast<const float4*>(&red4[w2][l2][cb + 4]);
            s0.x += r0.x; s0.y += r0.y; s0.z += r0.z; s0.w += r0.w;
            s1.x += r1.x; s1.y += r1.y; s1.z += r1.z; s1.w += r1.w;
        }
        float* P = part + ((size_t)sc * NH + n * H_ + (l2 >> 3)) * PART_STRIDE
                 + (4 * (l2 & 7) + a) * D_ + cb;
        *reinterpret_cast<float4*>(P)     = s0;
        *reinterpret_cast<float4*>(P + 4) = s1;
    }
    // ---- Ksum reduce ----
    __syncthreads();
    *reinterpret_cast<float4*>(&red4[w][l][0]) =
        make_float4(kp[0], kp[1], kp[2], kp[3]);
    __syncthreads();
    if (t < 64) {
        float4 s = make_float4(0.f, 0.f, 0.f, 0.f);
        #pragma unroll
        for (int w2 = 0; w2 < 4; ++w2) {
            const float4 r = *reinterpret_cast<const float4*>(&red4[w2][t][0]);
            s.x += r.x; s.y += r.y; s.z += r.z; s.w += r.w;
        }
        float* P2 = part + ((size_t)sc * NH + n * H_ + (t >> 3)) * PART_STRIDE
                  + D_ * D_ + ((t & 7) << 2);
        *reinterpret_cast<float4*>(P2) = s;
    }
}

// ---------------- reduce the SPL partials ----------------------------------
template<int SPL>
__global__ __launch_bounds__(256) void lin_attn_reduce(
        const float* __restrict__ part, float* __restrict__ red) {
    const int i = blockIdx.x * 256 + threadIdx.x;
    if (i >= NH * PART_STRIDE) return;
    float s = 0.0f;
    #pragma unroll 16
    for (int sc = 0; sc < SPL; ++sc)
        s += part[(size_t)sc * (NH * PART_STRIDE) + i];
    red[i] = s;
}

// ---------------- phase 2: out = (Q'.KV) * zinv, zinv = 1/(Q'.Ksum+eps) ----
// (round-7..11 version verbatim — ~20-26us, near its HBM floor)
__global__ __launch_bounds__(256) void lin_attn_phase2(
        const float* __restrict__ Qg, const float* __restrict__ red,
        float* __restrict__ outg) {
    constexpr int QTS = 32;           // Q tile rows
    constexpr int NLC = L_ / LCH;     // 32
    const int nh  = blockIdx.x / NLC;
    const int lcb = blockIdx.x % NLC;
    const int n = nh / H_, h = nh % H_;
    const int t = threadIdx.x;
    const int v  = t & 31;
    const int rb = t >> 5;            // 0..7
    const int r  = t >> 3;            // staging row 0..31
    const int c  = (t & 7) << 2;      // staging col

    __shared__ __align__(16) float Qt[QTS][D_];
    __shared__ float zinv_sh[QTS];

    // Pin this thread's KV column in registers (static indexing only).
    float kv[D_];
    const float* W = red + (size_t)nh * PART_STRIDE;
    #pragma unroll
    for (int d = 0; d < D_; ++d) kv[d] = W[d * D_ + v];
    // Ksum quad matching this thread's staging columns (runtime c -> load
    // from global, NOT a runtime-indexed register array).
    const float4 ksq = *reinterpret_cast<const float4*>(W + D_ * D_ + c);

    const size_t base = (size_t)n * L_ * H_ * D_ + (size_t)h * D_;
    const int l0 = lcb * LCH;
    for (int step = 0; step < LCH; step += QTS) {
        const float4 q4 = *reinterpret_cast<const float4*>(
            Qg + base + (size_t)(l0 + step + r) * (H_ * D_) + c);
        __syncthreads();   // previous Qt/zinv fully consumed
        float4 qf;
        qf.x = fmap(q4.x); qf.y = fmap(q4.y);
        qf.z = fmap(q4.z); qf.w = fmap(q4.w);
        *reinterpret_cast<float4*>(&Qt[r][c]) = qf;
        // per-row z: dot(q-quad, ksum-quad), folded across the 8 staging lanes
        float zp = qf.x * ksq.x + qf.y * ksq.y + qf.z * ksq.z + qf.w * ksq.w;
        zp += __shfl_xor(zp, 1);
        zp += __shfl_xor(zp, 2);
        zp += __shfl_xor(zp, 4);
        if ((t & 7) == 0) zinv_sh[r] = 1.0f / (zp + EPS_);
        __syncthreads();
        #pragma unroll
        for (int rr = 0; rr < 4; ++rr) {
            const int row = (rr << 3) + rb;
            float acc = 0.0f;
            #pragma unroll
            for (int d2 = 0; d2 < 16; ++d2) {   // b64 2-addr broadcast reads
                const float2 q = *reinterpret_cast<const float2*>(&Qt[row][d2 << 1]);
                acc += q.x * kv[(d2 << 1)] + q.y * kv[(d2 << 1) + 1];
            }
            outg[base + (size_t)(l0 + step + row) * (H_ * D_) + v] =
                acc * zinv_sh[row];
        }
    }
}

extern "C" void kernel_launch(void* const* d_in, const int* in_sizes, int n_in,
                              void* d_out, int out_size, void* d_ws, size_t ws_size,
                              hipStream_t stream) {
    const float* Q = (const float*)d_in[0];
    const float* K = (const float*)d_in[1];
    const float* V = (const float*)d_in[2];
    float* out  = (float*)d_out;
    float* part = (float*)d_ws;

    const size_t need128 = ((size_t)128 + 1) * NH * PART_STRIDE * sizeof(float);
    if (ws_size >= need128) {
        constexpr int SP = 128;  // 1024 blocks, part 34.6MB (proven fit)
        float* red = part + (size_t)SP * NH * PART_STRIDE;
        lin_attn_phase1<SP><<<N_ * SP, 256, 0, stream>>>(K, V, part);
        lin_attn_reduce<SP><<<(NH * PART_STRIDE + 255) / 256, 256, 0, stream>>>(part, red);
        lin_attn_phase2<<<NH * (L_ / LCH), 256, 0, stream>>>(Q, red, out);
    } else {
        constexpr int SP = 64;   // fallback: 512 blocks, part 17.3MB
        float* red = part + (size_t)SP * NH * PART_STRIDE;
        lin_attn_phase1<SP><<<N_ * SP, 256, 0, stream>>>(K, V, part);
        lin_attn_reduce<SP><<<(NH * PART_STRIDE + 255) / 256, 256, 0, stream>>>(part, red);
        lin_attn_phase2<<<NH * (L_ / LCH), 256, 0, stream>>>(Q, red, out);
    }
}

// Round 13
// 83.575 us; speedup vs baseline: 2.0927x; 2.0927x over previous
//
#include <hip/hip_runtime.h>

// Linear (kernelized) attention, N=8 L=S=8192 H=8 D=32, fp32.
// out = (Q'·(K'^T V)) / (Q'·Ksum + eps), Q'/K' = elu(x)+1.
// The /v_length and *v_length in the reference cancel exactly (2^13).

constexpr int N_ = 8, L_ = 8192, S_ = 8192, H_ = 8, D_ = 32;
constexpr int NH = N_ * H_;                  // 64 (n,h) pairs
constexpr int SPLIT = 32;                    // S-chunks per (n,h) -> 2048 blocks
constexpr int CS = S_ / SPLIT;               // 256 rows per block
constexpr int PART_STRIDE = D_ * D_ + D_;    // 1024 KV + 32 Ksum = 1056
constexpr int LCH = 256;                     // L-chunk per phase-2 block
constexpr float EPS_ = 1e-6f;
constexpr int HD = H_ * D_;                  // 256

typedef float f32x4 __attribute__((ext_vector_type(4)));

__device__ __forceinline__ float fmap(float x) {
    // elu(x)+1  (alpha=1): x>0 ? x+1 : exp(x)
    return x > 0.0f ? x + 1.0f : __expf(x);
}

// nontemporal 16B load: bypasses L2/L3 (nt flag). K/V are single-use streams.
__device__ __forceinline__ f32x4 ntl(const float* p) {
    return __builtin_nontemporal_load(reinterpret_cast<const f32x4*>(p));
}

// ---------------- phase 1: partial KV (D x D) + Ksum per (n,h,s-chunk) -----
// Round-7 structure verbatim (best measured: 57us, VGPR 52, no spill);
// ONLY change: stream loads are nontemporal (cache-bypass ablation).
__global__ __launch_bounds__(256, 4) void lin_attn_phase1(
        const float* __restrict__ Kg, const float* __restrict__ Vg,
        float* __restrict__ part) {
    const int blk = blockIdx.x;
    const int nh = blk / SPLIT;
    const int sc = blk % SPLIT;
    const int n = nh / H_, h = nh % H_;
    const int t = threadIdx.x;
    const int w = t >> 6;             // wave 0..3
    const int j = t & 63;             // lane
    const int half = j >> 5;          // 0/1: which of the 2 rows this beat
    const int jj = j & 31;
    const int d0 = (jj & 7) << 2;     // K quad: d0..d0+3
    const int v0 = (jj >> 3) << 3;    // V oct:  v0..v0+7

    __shared__ __align__(16) float red[4][1024];
    __shared__ __align__(16) float ksum_red[4][32];

    float acc[4][8];
    #pragma unroll
    for (int a = 0; a < 4; ++a)
        #pragma unroll
        for (int b = 0; b < 8; ++b) acc[a][b] = 0.0f;
    float kp[4] = {0.f, 0.f, 0.f, 0.f};

    const size_t base = (size_t)n * S_ * H_ * D_ + (size_t)h * D_;
    const int s0 = sc * CS;
    const float* kr = Kg + base + (size_t)(s0 + (w << 1) + half) * HD + d0;
    const float* vr = Vg + base + (size_t)(s0 + (w << 1) + half) * HD + v0;
    constexpr int STRIDE = 8 * HD;    // 8 rows per beat-step

#define BEAT(kq, va, vb) do {                                                  \
        float kd[4];                                                           \
        kd[0] = fmap((kq).x); kd[1] = fmap((kq).y);                            \
        kd[2] = fmap((kq).z); kd[3] = fmap((kq).w);                            \
        kp[0] += kd[0]; kp[1] += kd[1]; kp[2] += kd[2]; kp[3] += kd[3];        \
        const float vs[8] = {(va).x, (va).y, (va).z, (va).w,                   \
                             (vb).x, (vb).y, (vb).z, (vb).w};                  \
        _Pragma("unroll")                                                      \
        for (int a = 0; a < 4; ++a)                                            \
            _Pragma("unroll")                                                  \
            for (int bb = 0; bb < 8; ++bb)                                     \
                acc[a][bb] += kd[a] * vs[bb];                                  \
    } while (0)

    // prologue: beats 0 and 1 in flight (2-deep: 6 loads/wave outstanding)
    f32x4 kqA = ntl(kr);
    f32x4 vaA = ntl(vr);
    f32x4 vbA = ntl(vr + 4);
    f32x4 kqB = ntl(kr + STRIDE);
    f32x4 vaB = ntl(vr + STRIDE);
    f32x4 vbB = ntl(vr + STRIDE + 4);
    kr += 2 * STRIDE; vr += 2 * STRIDE;

    #pragma unroll 1
    for (int b = 0; b < (CS / 8 - 2) / 2; ++b) {   // 15 iters, 2 beats each
        f32x4 kqn = ntl(kr);
        f32x4 van = ntl(vr);
        f32x4 vbn = ntl(vr + 4);
        BEAT(kqA, vaA, vbA);
        kqA = kqn; vaA = van; vbA = vbn;
        kqn = ntl(kr + STRIDE);
        van = ntl(vr + STRIDE);
        vbn = ntl(vr + STRIDE + 4);
        BEAT(kqB, vaB, vbB);
        kqB = kqn; vaB = van; vbB = vbn;
        kr += 2 * STRIDE; vr += 2 * STRIDE;
    }
    BEAT(kqA, vaA, vbA);
    BEAT(kqB, vaB, vbB);
#undef BEAT

    // ---- cross-half (rows split even/odd) reduce, in-register ----
    #pragma unroll
    for (int a = 0; a < 4; ++a)
        #pragma unroll
        for (int bb = 0; bb < 8; ++bb)
            acc[a][bb] += __shfl_xor(acc[a][bb], 32);
    #pragma unroll
    for (int a = 0; a < 4; ++a) kp[a] += __shfl_xor(kp[a], 32);

    // ---- per-wave partial to LDS (lanes 0..31 hold the full sums) ----
    if (j < 32) {
        #pragma unroll
        for (int a = 0; a < 4; ++a) {
            *reinterpret_cast<float4*>(&red[w][(d0 + a) * D_ + v0]) =
                make_float4(acc[a][0], acc[a][1], acc[a][2], acc[a][3]);
            *reinterpret_cast<float4*>(&red[w][(d0 + a) * D_ + v0 + 4]) =
                make_float4(acc[a][4], acc[a][5], acc[a][6], acc[a][7]);
        }
        if (j < 8)   // kp duplicated across v-groups; one writer per d-quad
            *reinterpret_cast<float4*>(&ksum_red[w][j << 2]) =
                make_float4(kp[0], kp[1], kp[2], kp[3]);
    }
    __syncthreads();

    // ---- block-level reduce over the 4 waves, write partial ----
    float* P = part + ((size_t)sc * NH + nh) * PART_STRIDE;
    const int i4 = t << 2;            // 0,4,...,1020
    float4 s = make_float4(0.f, 0.f, 0.f, 0.f);
    #pragma unroll
    for (int w2 = 0; w2 < 4; ++w2) {
        const float4 rr = *reinterpret_cast<const float4*>(&red[w2][i4]);
        s.x += rr.x; s.y += rr.y; s.z += rr.z; s.w += rr.w;
    }
    *reinterpret_cast<float4*>(&P[i4]) = s;
    if (t < D_) {
        float ks = 0.f;
        #pragma unroll
        for (int w2 = 0; w2 < 4; ++w2) ks += ksum_red[w2][t];
        P[D_ * D_ + t] = ks;
    }
}

// ---------------- reduce the SPLIT partials -------------------------------
__global__ __launch_bounds__(256) void lin_attn_reduce(
        const float* __restrict__ part, float* __restrict__ red) {
    const int i = blockIdx.x * 256 + threadIdx.x;
    if (i >= NH * PART_STRIDE) return;
    float s = 0.0f;
    #pragma unroll 8
    for (int sc = 0; sc < SPLIT; ++sc)
        s += part[(size_t)sc * (NH * PART_STRIDE) + i];
    red[i] = s;
}

// ---------------- phase 2: out = (Q'.KV) * zinv, zinv = 1/(Q'.Ksum+eps) ----
// (round-7 version verbatim — measured ~21us, near its HBM floor)
__global__ __launch_bounds__(256) void lin_attn_phase2(
        const float* __restrict__ Qg, const float* __restrict__ red,
        float* __restrict__ outg) {
    constexpr int QTS = 32;           // Q tile rows
    constexpr int NLC = L_ / LCH;     // 32
    const int nh  = blockIdx.x / NLC;
    const int lcb = blockIdx.x % NLC;
    const int n = nh / H_, h = nh % H_;
    const int t = threadIdx.x;
    const int v  = t & 31;
    const int rb = t >> 5;            // 0..7
    const int r  = t >> 3;            // staging row 0..31
    const int c  = (t & 7) << 2;      // staging col

    __shared__ __align__(16) float Qt[QTS][D_];
    __shared__ float zinv_sh[QTS];

    // Pin this thread's KV column in registers (static indexing only).
    float kv[D_];
    const float* W = red + (size_t)nh * PART_STRIDE;
    #pragma unroll
    for (int d = 0; d < D_; ++d) kv[d] = W[d * D_ + v];
    // Ksum quad matching this thread's staging columns (runtime c -> load
    // from global, NOT a runtime-indexed register array).
    const float4 ksq = *reinterpret_cast<const float4*>(W + D_ * D_ + c);

    const size_t base = (size_t)n * L_ * H_ * D_ + (size_t)h * D_;
    const int l0 = lcb * LCH;
    for (int step = 0; step < LCH; step += QTS) {
        const float4 q4 = *reinterpret_cast<const float4*>(
            Qg + base + (size_t)(l0 + step + r) * (H_ * D_) + c);
        __syncthreads();   // previous Qt/zinv fully consumed
        float4 qf;
        qf.x = fmap(q4.x); qf.y = fmap(q4.y);
        qf.z = fmap(q4.z); qf.w = fmap(q4.w);
        *reinterpret_cast<float4*>(&Qt[r][c]) = qf;
        // per-row z: dot(q-quad, ksum-quad), folded across the 8 staging lanes
        float zp = qf.x * ksq.x + qf.y * ksq.y + qf.z * ksq.z + qf.w * ksq.w;
        zp += __shfl_xor(zp, 1);
        zp += __shfl_xor(zp, 2);
        zp += __shfl_xor(zp, 4);
        if ((t & 7) == 0) zinv_sh[r] = 1.0f / (zp + EPS_);
        __syncthreads();
        #pragma unroll
        for (int rr = 0; rr < 4; ++rr) {
            const int row = (rr << 3) + rb;
            float acc = 0.0f;
            #pragma unroll
            for (int d2 = 0; d2 < 16; ++d2) {   // b64 2-addr broadcast reads
                const float2 q = *reinterpret_cast<const float2*>(&Qt[row][d2 << 1]);
                acc += q.x * kv[(d2 << 1)] + q.y * kv[(d2 << 1) + 1];
            }
            outg[base + (size_t)(l0 + step + row) * (H_ * D_) + v] =
                acc * zinv_sh[row];
        }
    }
}

extern "C" void kernel_launch(void* const* d_in, const int* in_sizes, int n_in,
                              void* d_out, int out_size, void* d_ws, size_t ws_size,
                              hipStream_t stream) {
    const float* Q = (const float*)d_in[0];
    const float* K = (const float*)d_in[1];
    const float* V = (const float*)d_in[2];
    float* out  = (float*)d_out;
    float* part = (float*)d_ws;                                   // 32*64*1056 f32
    float* red  = part + (size_t)SPLIT * NH * PART_STRIDE;        // 64*1056 f32

    lin_attn_phase1<<<NH * SPLIT, 256, 0, stream>>>(K, V, part);
    lin_attn_reduce<<<(NH * PART_STRIDE + 255) / 256, 256, 0, stream>>>(part, red);
    lin_attn_phase2<<<NH * (L_ / LCH), 256, 0, stream>>>(Q, red, out);
}